// Round 3
// baseline (908.881 us; speedup 1.0000x reference)
//
#include <hip/hip_runtime.h>

#define NN 100000
#define NE 1600000
#define NT_E (NE / 16)
#define NT_N ((NN + 15) / 16)

typedef __attribute__((ext_vector_type(8))) short short8;
typedef __attribute__((ext_vector_type(4))) float f32x4;

// RNE float -> bf16 bits
__device__ __forceinline__ short f2b(float x) {
    unsigned u = __builtin_bit_cast(unsigned, x);
    u = (u + 0x7FFFu + ((u >> 16) & 1u)) >> 16;
    return (short)u;
}
__device__ __forceinline__ float b2f(unsigned short b) {
    return __builtin_bit_cast(float, (unsigned)b << 16);
}

__device__ __forceinline__ float selu_f(float x) {
    const float scale = 1.0507009873554805f;
    const float asc   = 1.7580993408473766f;  // alpha * scale
    return x > 0.f ? scale * x : asc * (__expf(x) - 1.f);
}

__device__ __forceinline__ short8 pack8(const float* __restrict__ p) {
    const f32x4 a = *reinterpret_cast<const f32x4*>(p);
    const f32x4 b = *reinterpret_cast<const f32x4*>(p + 4);
    short8 r;
#pragma unroll
    for (int j = 0; j < 4; ++j) { r[j] = f2b(a[j]); r[j + 4] = f2b(b[j]); }
    return r;
}

// non-temporal variant for the read-once edge_attr stream
__device__ __forceinline__ short8 pack8nt(const float* __restrict__ p) {
    const f32x4 a = __builtin_nontemporal_load(reinterpret_cast<const f32x4*>(p));
    const f32x4 b = __builtin_nontemporal_load(reinterpret_cast<const f32x4*>(p + 4));
    short8 r;
#pragma unroll
    for (int j = 0; j < 4; ++j) { r[j] = f2b(a[j]); r[j + 4] = f2b(b[j]); }
    return r;
}

__device__ __forceinline__ short8 ld_frag(const unsigned short* __restrict__ base, int idx, int lane) {
    return *reinterpret_cast<const short8*>(base + ((size_t)idx * 64 + lane) * 8);
}

__device__ __forceinline__ f32x4 mm(short8 a, short8 b, f32x4 c) {
    return __builtin_amdgcn_mfma_f32_16x16x32_bf16(a, b, c, 0, 0, 0);
}

// ---------- weight -> MFMA-fragment precompute (runs every call, ~3us) ----------
// frag(t,n), lane(p,q): 8 bf16 = W[t*32+q*8+j][n*16+p]; stored as [frag][lane][8] shorts
__global__ void frag_setup(const float* __restrict__ W1a, const float* __restrict__ W1b,
                           const float* __restrict__ W2a, const float* __restrict__ W2b,
                           unsigned short* __restrict__ fw) {
    const int lane = threadIdx.x;
    const int p = lane & 15, q = lane >> 4;
    const int f = blockIdx.x;
    const float* W; int idx; unsigned short* dst;
    if (f < 16)      { W = W1a; idx = f;      dst = fw; }
    else if (f < 24) { W = W1b; idx = f - 16; dst = fw + 16 * 512; }
    else if (f < 48) { W = W2a; idx = f - 24; dst = fw + 24 * 512; }
    else             { W = W2b; idx = f - 48; dst = fw + 48 * 512; }
    const int t = idx >> 2, n = idx & 3;
    const float* base = W + (t * 32 + q * 8) * 64 + n * 16 + p;
    unsigned short* o = dst + ((size_t)idx * 64 + lane) * 8;
#pragma unroll
    for (int j = 0; j < 8; ++j) o[j] = (unsigned short)f2b(base[j * 64]);
}

// ---------------- Edge MLP + scatter-add (packed bf16 atomics) ----------------
__global__ __launch_bounds__(256) void edge_kernel(
    const float* __restrict__ x, const int* __restrict__ row, const int* __restrict__ col,
    const float* __restrict__ ea,
    const unsigned short* __restrict__ fw1a, const float* __restrict__ b1a,
    const unsigned short* __restrict__ fw1b, const float* __restrict__ b1b,
    unsigned short* __restrict__ summed, float* __restrict__ counts)
{
    __shared__ __attribute__((aligned(16))) short hlds[4][16 * 72];
    const int lane = threadIdx.x & 63;
    const int wid  = threadIdx.x >> 6;
    const int p = lane & 15, q = lane >> 4;
    short* hl = hlds[wid];

    short8 B1[4][4], B2[2][4];
#pragma unroll
    for (int t = 0; t < 4; ++t)
#pragma unroll
        for (int n = 0; n < 4; ++n) B1[t][n] = ld_frag(fw1a, t * 4 + n, lane);
#pragma unroll
    for (int t = 0; t < 2; ++t)
#pragma unroll
        for (int n = 0; n < 4; ++n) B2[t][n] = ld_frag(fw1b, t * 4 + n, lane);
    float bias1[4], bias2[4];
#pragma unroll
    for (int n = 0; n < 4; ++n) { bias1[n] = b1a[n * 16 + p]; bias2[n] = b1b[n * 16 + p]; }

    const int tstride = gridDim.x * 4;
    int tile = blockIdx.x * 4 + wid;
    int rs = (tile < NT_E) ? row[tile * 16 + p] : 0;   // prefetched source index

    for (; tile < NT_E; tile += tstride) {
        const int e = tile * 16 + p;
        const float* xr = x + (size_t)rs * 64 + q * 8;
        const float* er = ea + (size_t)e * 64 + q * 8;
        short8 a0 = pack8(xr);
        short8 a1 = pack8(xr + 32);
        short8 a2 = pack8nt(er);
        short8 a3 = pack8nt(er + 32);

        const int tn = tile + tstride;                  // prefetch next tile's row index
        const int rs_next = (tn < NT_E) ? row[tn * 16 + p] : 0;

        int cd[4];
#pragma unroll
        for (int i = 0; i < 4; ++i) cd[i] = col[tile * 16 + q * 4 + i];

        f32x4 acc[4];
#pragma unroll
        for (int n = 0; n < 4; ++n) acc[n] = (f32x4){0.f, 0.f, 0.f, 0.f};
#pragma unroll
        for (int n = 0; n < 4; ++n) {
            acc[n] = mm(a0, B1[0][n], acc[n]);
            acc[n] = mm(a1, B1[1][n], acc[n]);
            acc[n] = mm(a2, B1[2][n], acc[n]);
            acc[n] = mm(a3, B1[3][n], acc[n]);
        }
        // selu+bias; D layout row=(q*4+i) edge, col=(n*16+p) feat -> LDS transpose
#pragma unroll
        for (int n = 0; n < 4; ++n)
#pragma unroll
            for (int i = 0; i < 4; ++i)
                hl[(q * 4 + i) * 72 + n * 16 + p] = f2b(selu_f(acc[n][i] + bias1[n]));

        short8 h0 = *reinterpret_cast<const short8*>(hl + p * 72 + q * 8);
        short8 h1 = *reinterpret_cast<const short8*>(hl + p * 72 + 32 + q * 8);

        f32x4 acc2[4];
#pragma unroll
        for (int n = 0; n < 4; ++n) acc2[n] = (f32x4){0.f, 0.f, 0.f, 0.f};
#pragma unroll
        for (int n = 0; n < 4; ++n) {
            acc2[n] = mm(h0, B2[0][n], acc2[n]);
            acc2[n] = mm(h1, B2[1][n], acc2[n]);
        }

        // packed bf16 atomic scatter: even lane p writes features (n*16+p, n*16+p+1)
#pragma unroll
        for (int n = 0; n < 4; ++n)
#pragma unroll
            for (int i = 0; i < 4; ++i) {
                const float v = acc2[n][i] + bias2[n];
                const float o = __shfl_xor(v, 1);
                if (!(p & 1)) {
                    unsigned pk = ((unsigned)(unsigned short)f2b(o) << 16) |
                                  (unsigned)(unsigned short)f2b(v);
                    unsigned long long addr =
                        (unsigned long long)(summed + (size_t)cd[i] * 64 + n * 16 + p);
                    asm volatile("global_atomic_pk_add_bf16 %0, %1, off"
                                 :: "v"(addr), "v"(pk) : "memory");
                }
            }
        if (lane < 16) unsafeAtomicAdd(&counts[col[e]], 1.0f);
        rs = rs_next;
    }
}

// ---------------- Node MLP ----------------
__global__ __launch_bounds__(256) void node_kernel(
    const float* __restrict__ x, const float* __restrict__ u, const int* __restrict__ batch,
    const unsigned short* __restrict__ summed, const float* __restrict__ counts,
    const unsigned short* __restrict__ fw2a, const float* __restrict__ b2a,
    const unsigned short* __restrict__ fw2b, const float* __restrict__ b2b,
    float* __restrict__ out)
{
    __shared__ __attribute__((aligned(16))) short hlds[4][16 * 72];
    const int lane = threadIdx.x & 63;
    const int wid  = threadIdx.x >> 6;
    const int p = lane & 15, q = lane >> 4;
    short* hl = hlds[wid];

    short8 BA[6][4], BB[2][4];
#pragma unroll
    for (int t = 0; t < 6; ++t)
#pragma unroll
        for (int n = 0; n < 4; ++n) BA[t][n] = ld_frag(fw2a, t * 4 + n, lane);
#pragma unroll
    for (int t = 0; t < 2; ++t)
#pragma unroll
        for (int n = 0; n < 4; ++n) BB[t][n] = ld_frag(fw2b, t * 4 + n, lane);
    float bias1[4], bias2[4];
#pragma unroll
    for (int n = 0; n < 4; ++n) { bias1[n] = b2a[n * 16 + p]; bias2[n] = b2b[n * 16 + p]; }

    const int tstride = gridDim.x * 4;
    for (int tile = blockIdx.x * 4 + wid; tile < NT_N; tile += tstride) {
        const int v = tile * 16 + p;
        const float* xr = x + (size_t)v * 64 + q * 8;
        short8 a0 = pack8(xr);
        short8 a1 = pack8(xr + 32);

        const float rc = 1.f / fmaxf(counts[v], 1.f);
        const unsigned short* sr = summed + (size_t)v * 64 + q * 8;
        short8 s0 = *reinterpret_cast<const short8*>(sr);
        short8 s1 = *reinterpret_cast<const short8*>(sr + 32);
        short8 a2, a3;
#pragma unroll
        for (int j = 0; j < 8; ++j) {
            a2[j] = f2b(b2f((unsigned short)s0[j]) * rc);
            a3[j] = f2b(b2f((unsigned short)s1[j]) * rc);
        }
        const int g = batch[v];
        const float* ur = u + (size_t)g * 64 + q * 8;
        short8 a4 = pack8(ur);
        short8 a5 = pack8(ur + 32);

        f32x4 acc[4];
#pragma unroll
        for (int n = 0; n < 4; ++n) acc[n] = (f32x4){0.f, 0.f, 0.f, 0.f};
#pragma unroll
        for (int n = 0; n < 4; ++n) {
            acc[n] = mm(a0, BA[0][n], acc[n]);
            acc[n] = mm(a1, BA[1][n], acc[n]);
            acc[n] = mm(a2, BA[2][n], acc[n]);
            acc[n] = mm(a3, BA[3][n], acc[n]);
            acc[n] = mm(a4, BA[4][n], acc[n]);
            acc[n] = mm(a5, BA[5][n], acc[n]);
        }
#pragma unroll
        for (int n = 0; n < 4; ++n)
#pragma unroll
            for (int i = 0; i < 4; ++i)
                hl[(q * 4 + i) * 72 + n * 16 + p] = f2b(selu_f(acc[n][i] + bias1[n]));

        short8 h0 = *reinterpret_cast<const short8*>(hl + p * 72 + q * 8);
        short8 h1 = *reinterpret_cast<const short8*>(hl + p * 72 + 32 + q * 8);

        f32x4 acc2[4];
#pragma unroll
        for (int n = 0; n < 4; ++n) acc2[n] = (f32x4){0.f, 0.f, 0.f, 0.f};
#pragma unroll
        for (int n = 0; n < 4; ++n) {
            acc2[n] = mm(h0, BB[0][n], acc2[n]);
            acc2[n] = mm(h1, BB[1][n], acc2[n]);
        }
#pragma unroll
        for (int n = 0; n < 4; ++n)
#pragma unroll
            for (int i = 0; i < 4; ++i)
                out[((size_t)tile * 16 + q * 4 + i) * 64 + n * 16 + p] = acc2[n][i] + bias2[n];
    }
}

extern "C" void kernel_launch(void* const* d_in, const int* in_sizes, int n_in,
                              void* d_out, int out_size, void* d_ws, size_t ws_size,
                              hipStream_t stream) {
    const float* x     = (const float*)d_in[0];
    const int*   ei    = (const int*)d_in[1];
    const float* ea    = (const float*)d_in[2];
    const float* u     = (const float*)d_in[3];
    const int*   batch = (const int*)d_in[4];
    const float* W1a   = (const float*)d_in[5];
    const float* b1a   = (const float*)d_in[6];
    const float* W1b   = (const float*)d_in[7];
    const float* b1b   = (const float*)d_in[8];
    const float* W2a   = (const float*)d_in[9];
    const float* b2a   = (const float*)d_in[10];
    const float* W2b   = (const float*)d_in[11];
    const float* b2b   = (const float*)d_in[12];
    float* out = (float*)d_out;

    // ws layout: summed bf16 [NN*64] (12.8MB) | counts f32 [NN] (0.4MB) | frag buf (57KB)
    unsigned short* summed = (unsigned short*)d_ws;
    float* counts = (float*)((char*)d_ws + (size_t)NN * 64 * 2);
    unsigned short* fw = (unsigned short*)((char*)d_ws + 13200000);
    const unsigned short* fw1a = fw;
    const unsigned short* fw1b = fw + 16 * 512;
    const unsigned short* fw2a = fw + 24 * 512;
    const unsigned short* fw2b = fw + 48 * 512;

    hipMemsetAsync(d_ws, 0, 13200000, stream);
    frag_setup<<<56, 64, 0, stream>>>(W1a, W1b, W2a, W2b, fw);

    const int* row = ei;
    const int* col = ei + NE;
    edge_kernel<<<1024, 256, 0, stream>>>(x, row, col, ea, fw1a, b1a, fw1b, b1b, summed, counts);
    node_kernel<<<1024, 256, 0, stream>>>(x, u, batch, summed, counts, fw2a, b2a, fw2b, b2b, out);
}

// Round 6
// 893.812 us; speedup vs baseline: 1.0169x; 1.0169x over previous
//
#include <hip/hip_runtime.h>

#define NN 100000
#define NE 1600000
#define NT_N (NN / 16)        // 6250 node tiles (NN divisible by 16)
#define NBLK_SCAN 98          // 98*1024 = 100352 >= NN

typedef __attribute__((ext_vector_type(8))) short short8;
typedef __attribute__((ext_vector_type(4))) float f32x4;

// RNE float -> bf16 bits
__device__ __forceinline__ short f2b(float x) {
    unsigned u = __builtin_bit_cast(unsigned, x);
    u = (u + 0x7FFFu + ((u >> 16) & 1u)) >> 16;
    return (short)u;
}

__device__ __forceinline__ float selu_f(float x) {
    const float scale = 1.0507009873554805f;
    const float asc   = 1.7580993408473766f;  // alpha * scale
    return x > 0.f ? scale * x : asc * (__expf(x) - 1.f);
}

__device__ __forceinline__ short8 pack8(const float* __restrict__ p) {
    const f32x4 a = *reinterpret_cast<const f32x4*>(p);
    const f32x4 b = *reinterpret_cast<const f32x4*>(p + 4);
    short8 r;
#pragma unroll
    for (int j = 0; j < 4; ++j) { r[j] = f2b(a[j]); r[j + 4] = f2b(b[j]); }
    return r;
}

__device__ __forceinline__ short8 pack8nt(const float* __restrict__ p) {
    const f32x4 a = __builtin_nontemporal_load(reinterpret_cast<const f32x4*>(p));
    const f32x4 b = __builtin_nontemporal_load(reinterpret_cast<const f32x4*>(p + 4));
    short8 r;
#pragma unroll
    for (int j = 0; j < 4; ++j) { r[j] = f2b(a[j]); r[j + 4] = f2b(b[j]); }
    return r;
}

__device__ __forceinline__ short8 ld_frag(const unsigned short* __restrict__ base, int idx, int lane) {
    return *reinterpret_cast<const short8*>(base + ((size_t)idx * 64 + lane) * 8);
}

__device__ __forceinline__ f32x4 mm(short8 a, short8 b, f32x4 c) {
    return __builtin_amdgcn_mfma_f32_16x16x32_bf16(a, b, c, 0, 0, 0);
}

// ---------- weight -> MFMA-fragment precompute ----------
// frag(t,n), lane(p,q): 8 bf16 = W[t*32+q*8+j][n*16+p]
__global__ void frag_setup(const float* __restrict__ W1a, const float* __restrict__ W1b,
                           const float* __restrict__ W2a, const float* __restrict__ W2b,
                           unsigned short* __restrict__ fw) {
    const int lane = threadIdx.x;
    const int p = lane & 15, q = lane >> 4;
    const int f = blockIdx.x;
    const float* W; int idx; unsigned short* dst;
    if (f < 16)      { W = W1a; idx = f;      dst = fw; }
    else if (f < 24) { W = W1b; idx = f - 16; dst = fw + 16 * 512; }
    else if (f < 48) { W = W2a; idx = f - 24; dst = fw + 24 * 512; }
    else             { W = W2b; idx = f - 48; dst = fw + 48 * 512; }
    const int t = idx >> 2, n = idx & 3;
    const float* base = W + (t * 32 + q * 8) * 64 + n * 16 + p;
    unsigned short* o = dst + ((size_t)idx * 64 + lane) * 8;
#pragma unroll
    for (int j = 0; j < 8; ++j) o[j] = (unsigned short)f2b(base[j * 64]);
}

// ---------- CSR build ----------
__global__ void hist_kernel(const int* __restrict__ col, int* __restrict__ counts) {
    int i = blockIdx.x * blockDim.x + threadIdx.x;
    const int stride = gridDim.x * blockDim.x;
    for (; i < NE; i += stride) atomicAdd(&counts[col[i]], 1);
}

__global__ __launch_bounds__(1024) void scanA(const int* __restrict__ counts,
                                              int* __restrict__ starts, int* __restrict__ btot) {
    __shared__ int sh[1024];
    const int tid = threadIdx.x;
    const int i = blockIdx.x * 1024 + tid;
    const int v = (i < NN) ? counts[i] : 0;
    sh[tid] = v; __syncthreads();
#pragma unroll
    for (int off = 1; off < 1024; off <<= 1) {
        int t = (tid >= off) ? sh[tid - off] : 0;
        __syncthreads();
        sh[tid] += t; __syncthreads();
    }
    starts[i] = sh[tid] - v;   // exclusive scan within chunk
    if (tid == 1023) btot[blockIdx.x] = sh[1023];
}

__global__ __launch_bounds__(128) void scanB(const int* __restrict__ btot, int* __restrict__ boff) {
    __shared__ int sh[128];
    const int tid = threadIdx.x;
    const int v = (tid < NBLK_SCAN) ? btot[tid] : 0;
    sh[tid] = v; __syncthreads();
#pragma unroll
    for (int off = 1; off < 128; off <<= 1) {
        int t = (tid >= off) ? sh[tid - off] : 0;
        __syncthreads();
        sh[tid] += t; __syncthreads();
    }
    if (tid < NBLK_SCAN) boff[tid] = sh[tid] - v;
}

__global__ __launch_bounds__(1024) void scanC(int* __restrict__ starts, const int* __restrict__ boff,
                                              int* __restrict__ cursor) {
    const int i = blockIdx.x * 1024 + threadIdx.x;
    const int s = starts[i] + boff[blockIdx.x];
    starts[i] = s;
    if (i < NN) cursor[i] = s;
}

__global__ void scatter_kernel(const int* __restrict__ col, int* __restrict__ cursor,
                               int* __restrict__ payload) {
    int i = blockIdx.x * blockDim.x + threadIdx.x;
    const int stride = gridDim.x * blockDim.x;
    for (; i < NE; i += stride) {
        const int c = col[i];
        const int pos = atomicAdd(&cursor[c], 1);
        payload[pos] = i;
    }
}

// ---------- Edge layer-1a + per-node register reduction ----------
// hmean[v] = (1/k) * sum_{e->v} selu(cat(x[row_e], ea_e) @ W1a + b1a)   (bf16)
__global__ __launch_bounds__(256) void edge_gather(
    const float* __restrict__ x, const int* __restrict__ row, const float* __restrict__ ea,
    const int* __restrict__ starts, const int* __restrict__ payload,
    const unsigned short* __restrict__ fw1a, const float* __restrict__ b1a,
    unsigned short* __restrict__ hmean)
{
    const int lane = threadIdx.x & 63;
    const int wid  = threadIdx.x >> 6;
    const int p = lane & 15, q = lane >> 4;

    short8 B1[4][4];
#pragma unroll
    for (int t = 0; t < 4; ++t)
#pragma unroll
        for (int n = 0; n < 4; ++n) B1[t][n] = ld_frag(fw1a, t * 4 + n, lane);
    float bias1[4];
#pragma unroll
    for (int n = 0; n < 4; ++n) bias1[n] = b1a[n * 16 + p];

    const int nwave = gridDim.x * 4;
    for (int v = blockIdx.x * 4 + wid; v < NN; v += nwave) {
        const int s0 = starts[v];
        const int k  = starts[v + 1] - s0;
        float hsum[4] = {0.f, 0.f, 0.f, 0.f};
        if (k > 0) {
            const int ntile = (k + 15) >> 4;
            for (int t = 0; t < ntile; ++t) {
                const int slot = t * 16 + p;
                const int sc = slot < k ? slot : k - 1;       // clamp pad lanes
                const int e  = payload[s0 + sc];
                const int rs = row[e];
                const float* xr = x + (size_t)rs * 64 + q * 8;
                const float* er = ea + (size_t)e * 64 + q * 8;
                short8 a0 = pack8(xr);
                short8 a1 = pack8(xr + 32);
                short8 a2 = pack8nt(er);
                short8 a3 = pack8nt(er + 32);

                f32x4 acc[4];
#pragma unroll
                for (int n = 0; n < 4; ++n) acc[n] = (f32x4){0.f, 0.f, 0.f, 0.f};
#pragma unroll
                for (int n = 0; n < 4; ++n) {
                    acc[n] = mm(a0, B1[0][n], acc[n]);
                    acc[n] = mm(a1, B1[1][n], acc[n]);
                    acc[n] = mm(a2, B1[2][n], acc[n]);
                    acc[n] = mm(a3, B1[3][n], acc[n]);
                }
                const int rbase = t * 16 + q * 4;             // D row = edge slot
#pragma unroll
                for (int n = 0; n < 4; ++n)
#pragma unroll
                    for (int i = 0; i < 4; ++i)
                        if (rbase + i < k) hsum[n] += selu_f(acc[n][i] + bias1[n]);
            }
        }
        // reduce across q-lanes (rows held by q groups)
#pragma unroll
        for (int n = 0; n < 4; ++n) {
            hsum[n] += __shfl_xor(hsum[n], 16);
            hsum[n] += __shfl_xor(hsum[n], 32);
        }
        const float rk = (k > 0) ? 1.f / (float)k : 0.f;
        if (q == 0) {
#pragma unroll
            for (int n = 0; n < 4; ++n)
                hmean[(size_t)v * 64 + n * 16 + p] = (unsigned short)f2b(hsum[n] * rk);
        }
    }
}

// ---------- Node MLP: m = hmean@W1b + b1b (masked), then layer 2 ----------
__global__ __launch_bounds__(256) void node_kernel(
    const float* __restrict__ x, const float* __restrict__ u, const int* __restrict__ batch,
    const unsigned short* __restrict__ hmean, const int* __restrict__ starts,
    const unsigned short* __restrict__ fw1b, const float* __restrict__ b1b,
    const unsigned short* __restrict__ fw2a, const float* __restrict__ b2a,
    const unsigned short* __restrict__ fw2b, const float* __restrict__ b2b,
    float* __restrict__ out)
{
    __shared__ __attribute__((aligned(16))) short hlds[4][16 * 72];
    const int lane = threadIdx.x & 63;
    const int wid  = threadIdx.x >> 6;
    const int p = lane & 15, q = lane >> 4;
    short* hl = hlds[wid];

    short8 BM[2][4], BA[6][4], BB[2][4];
#pragma unroll
    for (int t = 0; t < 2; ++t)
#pragma unroll
        for (int n = 0; n < 4; ++n) BM[t][n] = ld_frag(fw1b, t * 4 + n, lane);
#pragma unroll
    for (int t = 0; t < 6; ++t)
#pragma unroll
        for (int n = 0; n < 4; ++n) BA[t][n] = ld_frag(fw2a, t * 4 + n, lane);
#pragma unroll
    for (int t = 0; t < 2; ++t)
#pragma unroll
        for (int n = 0; n < 4; ++n) BB[t][n] = ld_frag(fw2b, t * 4 + n, lane);
    float biasm[4], bias1[4], bias2[4];
#pragma unroll
    for (int n = 0; n < 4; ++n) {
        biasm[n] = b1b[n * 16 + p];
        bias1[n] = b2a[n * 16 + p];
        bias2[n] = b2b[n * 16 + p];
    }

    const int tstride = gridDim.x * 4;
    for (int tile = blockIdx.x * 4 + wid; tile < NT_N; tile += tstride) {
        const int v = tile * 16 + p;
        // ---- m = hmean @ W1b + b1b (zero for empty nodes) ----
        const unsigned short* hr = hmean + (size_t)v * 64 + q * 8;
        short8 m0 = *reinterpret_cast<const short8*>(hr);
        short8 m1 = *reinterpret_cast<const short8*>(hr + 32);
        f32x4 mac[4];
#pragma unroll
        for (int n = 0; n < 4; ++n) mac[n] = (f32x4){0.f, 0.f, 0.f, 0.f};
#pragma unroll
        for (int n = 0; n < 4; ++n) {
            mac[n] = mm(m0, BM[0][n], mac[n]);
            mac[n] = mm(m1, BM[1][n], mac[n]);
        }
        const int vr = tile * 16 + q * 4;                    // D row -> node vr+i
        int sA[5];
#pragma unroll
        for (int j = 0; j < 5; ++j) sA[j] = starts[vr + j];
#pragma unroll
        for (int i = 0; i < 4; ++i) {
            const bool nz = sA[i + 1] > sA[i];
#pragma unroll
            for (int n = 0; n < 4; ++n)
                hl[(q * 4 + i) * 72 + n * 16 + p] = f2b(nz ? mac[n][i] + biasm[n] : 0.f);
        }
        short8 a2 = *reinterpret_cast<const short8*>(hl + p * 72 + q * 8);
        short8 a3 = *reinterpret_cast<const short8*>(hl + p * 72 + 32 + q * 8);

        // ---- layer 2a: cat(x, m, u) @ W2a ----
        const float* xr = x + (size_t)v * 64 + q * 8;
        short8 a0 = pack8(xr);
        short8 a1 = pack8(xr + 32);
        const int g = batch[v];
        const float* ur = u + (size_t)g * 64 + q * 8;
        short8 a4 = pack8(ur);
        short8 a5 = pack8(ur + 32);

        f32x4 acc[4];
#pragma unroll
        for (int n = 0; n < 4; ++n) acc[n] = (f32x4){0.f, 0.f, 0.f, 0.f};
#pragma unroll
        for (int n = 0; n < 4; ++n) {
            acc[n] = mm(a0, BA[0][n], acc[n]);
            acc[n] = mm(a1, BA[1][n], acc[n]);
            acc[n] = mm(a2, BA[2][n], acc[n]);
            acc[n] = mm(a3, BA[3][n], acc[n]);
            acc[n] = mm(a4, BA[4][n], acc[n]);
            acc[n] = mm(a5, BA[5][n], acc[n]);
        }
#pragma unroll
        for (int n = 0; n < 4; ++n)
#pragma unroll
            for (int i = 0; i < 4; ++i)
                hl[(q * 4 + i) * 72 + n * 16 + p] = f2b(selu_f(acc[n][i] + bias1[n]));

        short8 h0 = *reinterpret_cast<const short8*>(hl + p * 72 + q * 8);
        short8 h1 = *reinterpret_cast<const short8*>(hl + p * 72 + 32 + q * 8);

        f32x4 acc2[4];
#pragma unroll
        for (int n = 0; n < 4; ++n) acc2[n] = (f32x4){0.f, 0.f, 0.f, 0.f};
#pragma unroll
        for (int n = 0; n < 4; ++n) {
            acc2[n] = mm(h0, BB[0][n], acc2[n]);
            acc2[n] = mm(h1, BB[1][n], acc2[n]);
        }
#pragma unroll
        for (int n = 0; n < 4; ++n)
#pragma unroll
            for (int i = 0; i < 4; ++i)
                out[((size_t)tile * 16 + q * 4 + i) * 64 + n * 16 + p] = acc2[n][i] + bias2[n];
    }
}

extern "C" void kernel_launch(void* const* d_in, const int* in_sizes, int n_in,
                              void* d_out, int out_size, void* d_ws, size_t ws_size,
                              hipStream_t stream) {
    const float* x     = (const float*)d_in[0];
    const int*   ei    = (const int*)d_in[1];
    const float* ea    = (const float*)d_in[2];
    const float* u     = (const float*)d_in[3];
    const int*   batch = (const int*)d_in[4];
    const float* W1a   = (const float*)d_in[5];
    const float* b1a   = (const float*)d_in[6];
    const float* W1b   = (const float*)d_in[7];
    const float* b1b   = (const float*)d_in[8];
    const float* W2a   = (const float*)d_in[9];
    const float* b2a   = (const float*)d_in[10];
    const float* W2b   = (const float*)d_in[11];
    const float* b2b   = (const float*)d_in[12];
    float* out = (float*)d_out;

    // ws layout (bytes), total ~20.46 MB (< 26 MB proven available):
    char* ws = (char*)d_ws;
    int*            payload = (int*)(ws + 0);                   //  6,400,000
    unsigned short* hmean   = (unsigned short*)(ws + 6400000);  // 12,800,000
    int*            starts  = (int*)(ws + 19200000);            //    401,408 (98*1024 ints)
    int*            cursor  = (int*)(ws + 19601408);            //    400,000
    int*            counts  = (int*)(ws + 20001408);            //    400,000
    int*            btot    = (int*)(ws + 20401408);            //        512
    int*            boff    = (int*)(ws + 20401920);            //        512
    unsigned short* fw      = (unsigned short*)(ws + 20402432); //     57,344

    const int* row = ei;
    const int* col = ei + NE;

    hipMemsetAsync(counts, 0, NN * sizeof(int), stream);
    frag_setup<<<56, 64, 0, stream>>>(W1a, W1b, W2a, W2b, fw);
    hist_kernel<<<1024, 256, 0, stream>>>(col, counts);
    scanA<<<NBLK_SCAN, 1024, 0, stream>>>(counts, starts, btot);
    scanB<<<1, 128, 0, stream>>>(btot, boff);
    scanC<<<NBLK_SCAN, 1024, 0, stream>>>(starts, boff, cursor);
    scatter_kernel<<<1024, 256, 0, stream>>>(col, cursor, payload);
    edge_gather<<<2048, 256, 0, stream>>>(x, row, ea, starts, payload,
                                          fw, b1a, hmean);
    node_kernel<<<1024, 256, 0, stream>>>(x, u, batch, hmean, starts,
                                          fw + 16 * 512, b1b, fw + 24 * 512, b2a,
                                          fw + 48 * 512, b2b, out);
}